// Round 12
// baseline (176.283 us; speedup 1.0000x reference)
//
#include <hip/hip_runtime.h>
#include <hip/hip_bf16.h>

typedef __hip_bfloat16 bf16;
typedef unsigned short ushort;
typedef unsigned int uint;
typedef __attribute__((ext_vector_type(8))) short short8;
typedef __attribute__((ext_vector_type(4))) float f32x4;

#define Bn 8
#define Cn 256
#define Nn 4096          // H*W
#define Mn 1024          // pooled
#define EPSf 1e-5f

__device__ __forceinline__ float b2f(const bf16 v){ return __bfloat162float(v); }
__device__ __forceinline__ ushort f2bu(float f){
  uint u = __float_as_uint(f);
  return (ushort)((u + 0x7FFFu + ((u >> 16) & 1u)) >> 16);
}

// ---- fragment-tiled layouts (1KB contiguous lane-linear blocks, v8-proven) ----
// xTt: (b, p16, kc)  idx = ((b*256+p16)*8+kc)*512 + lane*8
// Wct/Wwt: (o16, kc) idx = (o16*8+kc)*512 + lane*8
// K:  (b, k16, half) idx = ((b*64+k16)*2+half)*512 + lane*8
// Vt: (b, mt, n16, half) idx = (((b*16+mt)*16+n16)*2+half)*512 + lane*8

// ---------------- transpose: x[b][c][p] fp32 -> xTt fragment-tiled bf16
__global__ __launch_bounds__(256) void transpose_kernel(
    const float* __restrict__ x, bf16* __restrict__ xT)
{
  __shared__ float xs[64][65];
  const int t = threadIdx.x;
  const int p0 = blockIdx.x*64, c0 = blockIdx.y*64, b = blockIdx.z;
  #pragma unroll
  for (int i = 0; i < 16; ++i) {
    int idx = t + i*256; int cl = idx >> 6, pl = idx & 63;
    xs[cl][pl] = x[((long)(b*Cn) + c0 + cl)*Nn + p0 + pl];
  }
  __syncthreads();
  ushort* xt = (ushort*)xT;
  const int ql = t & 15, quad = (t >> 4) & 3, w = t >> 6;
  #pragma unroll
  for (int i = 0; i < 2; ++i) {
    int f = w + i*4;                  // 0..7
    int p16f = f >> 1, kcf = f & 1;
    int pl = p16f*16 + ql;
    int ch0 = kcf*32 + quad*8;
    uint u[4];
    #pragma unroll
    for (int k = 0; k < 4; ++k)
      u[k] = (uint)f2bu(xs[ch0 + 2*k][pl]) | ((uint)f2bu(xs[ch0 + 2*k + 1][pl]) << 16);
    long base = ((long)b*2048 + ((p0>>4) + p16f)*8 + (c0>>5) + kcf)*512;
    *(uint4*)(xt + base + (t & 63)*8) = make_uint4(u[0], u[1], u[2], u[3]);
  }
}

// ---------------- merged prep: combined weights -> tiled Wct + bcomb,
// and W_w -> tiled Wwt.  grid 640: r<384 = Wct row r; r>=384 = Wwt row r-384.
__global__ __launch_bounds__(256) void wprep_kernel(
    const float* __restrict__ tw, const float* __restrict__ tb,
    const float* __restrict__ pw, const float* __restrict__ pb,
    const float* __restrict__ gw, const float* __restrict__ gb,
    const float* __restrict__ Ww,
    bf16* __restrict__ Wcomb, float* __restrict__ bcomb,
    bf16* __restrict__ Wwt)
{
  const int rb = blockIdx.x, c = threadIdx.x;
  if (rb < 384) {
    const int r = rb;
    float v;
    if (r < 64)        v = (c < 64)  ? tw[r*64 + c]            : 0.f;
    else if (r < 128)  v = (c >= 64) ? pw[(r-64)*192 + (c-64)] : 0.f;
    else               v = gw[(r-128)*256 + c];
    ((ushort*)Wcomb)[((r>>4)*8 + (c>>5))*512 + (((c&31)>>3)*16 + (r&15))*8 + (c&7)]
        = f2bu(v);
    if (c == 0)
      bcomb[r] = (r < 64) ? tb[r] : (r < 128) ? pb[r-64] : gb[r-128];
  } else {
    const int r = rb - 384;
    ((ushort*)Wwt)[((r>>4)*8 + (c>>5))*512 + (((c&31)>>3)*16 + (r&15))*8 + (c&7)]
        = f2bu(Ww[r*256 + c]);
  }
}

// ---------------- fused front GEMM + pooling: zero-LDS main loop (round-6).
__global__ __launch_bounds__(256) void gemm384_kernel(
    const bf16* __restrict__ xTt, const bf16* __restrict__ Wct,
    const float* __restrict__ bcomb, bf16* __restrict__ Q,
    bf16* __restrict__ K, bf16* __restrict__ Vt)
{
  __shared__ float Pb[2][128][33];
  const int t = threadIdx.x;
  const int px = blockIdx.x, o0 = blockIdx.y*128, b = blockIdx.z;
  const int p0 = px*128;
  const int lane = t & 63, w = t >> 6;
  const int ql = lane & 15, quad = lane >> 4;
  const int wm = (w & 1)*64, wn = (w >> 1)*64;
  const ushort* xu = (const ushort*)xTt;
  const ushort* wu = (const ushort*)Wct;

  const ushort* aB[4]; const ushort* bB[4];
  #pragma unroll
  for (int mi = 0; mi < 4; ++mi)
    aB[mi] = xu + (((long)b*256 + px*8 + (wm>>4) + mi)*8)*512 + lane*8;
  #pragma unroll
  for (int ni = 0; ni < 4; ++ni)
    bB[ni] = wu + ((long)(((o0 + wn)>>4) + ni)*8)*512 + lane*8;

  f32x4 acc[4][4];
  #pragma unroll
  for (int i = 0; i < 4; ++i)
    #pragma unroll
    for (int j = 0; j < 4; ++j) acc[i][j] = (f32x4){0.f,0.f,0.f,0.f};

  short8 aX[4], bX[4], aY[4], bY[4];
  #pragma unroll
  for (int i = 0; i < 4; ++i) {
    aX[i] = *(const short8*)(aB[i]);
    bX[i] = *(const short8*)(bB[i]);
    aY[i] = *(const short8*)(aB[i] + 512);
    bY[i] = *(const short8*)(bB[i] + 512);
  }
  #pragma unroll
  for (int kc2 = 0; kc2 < 4; ++kc2) {
    #pragma unroll
    for (int mi = 0; mi < 4; ++mi)
      #pragma unroll
      for (int ni = 0; ni < 4; ++ni)
        acc[mi][ni] = __builtin_amdgcn_mfma_f32_16x16x32_bf16(aX[mi], bX[ni], acc[mi][ni], 0, 0, 0);
    if (kc2 < 3) {
      #pragma unroll
      for (int i = 0; i < 4; ++i) {
        aX[i] = *(const short8*)(aB[i] + (kc2*2 + 2)*512);
        bX[i] = *(const short8*)(bB[i] + (kc2*2 + 2)*512);
      }
    }
    #pragma unroll
    for (int mi = 0; mi < 4; ++mi)
      #pragma unroll
      for (int ni = 0; ni < 4; ++ni)
        acc[mi][ni] = __builtin_amdgcn_mfma_f32_16x16x32_bf16(aY[mi], bY[ni], acc[mi][ni], 0, 0, 0);
    if (kc2 < 3) {
      #pragma unroll
      for (int i = 0; i < 4; ++i) {
        aY[i] = *(const short8*)(aB[i] + (kc2*2 + 3)*512);
        bY[i] = *(const short8*)(bB[i] + (kc2*2 + 3)*512);
      }
    }
  }

  float bias[4];
  #pragma unroll
  for (int ni = 0; ni < 4; ++ni) bias[ni] = bcomb[o0 + wn + ni*16 + ql];

  if (o0 == 0 && wn == 0) {
    #pragma unroll
    for (int mi = 0; mi < 4; ++mi)
      #pragma unroll
      for (int ni = 0; ni < 4; ++ni)
        #pragma unroll
        for (int r = 0; r < 4; ++r) {
          int p = p0 + wm + mi*16 + quad*4 + r;
          Q[((long)(b*Nn) + p)*64 + ni*16 + ql] = __float2bfloat16(acc[mi][ni][r] + bias[ni]);
        }
  }
  __syncthreads();
  if (o0 != 0 || wn == 64) {
    int g = w & 1;
    #pragma unroll
    for (int mi = 0; mi < 4; ++mi)
      #pragma unroll
      for (int ni = 0; ni < 4; ++ni) {
        float a0 = acc[mi][ni][0] + bias[ni], a1 = acc[mi][ni][1] + bias[ni];
        float a2 = acc[mi][ni][2] + bias[ni], a3 = acc[mi][ni][3] + bias[ni];
        int o = wn + ni*16 + ql;
        int wp = mi*8 + quad*2;
        Pb[g][o][wp]     = fmaxf(a0, a1);
        Pb[g][o][wp + 1] = fmaxf(a2, a3);
      }
  }
  __syncthreads();
  if (o0 == 0) {
    int wp = t & 31, og = t >> 5;
    ushort kv[8];
    #pragma unroll
    for (int j = 0; j < 8; ++j) {
      int o = 64 + og*8 + j;
      kv[j] = f2bu(fmaxf(Pb[0][o][wp], Pb[1][o][wp]));
    }
    long kidx = ((long)(b*64) + px*2 + (wp>>4))*1024 + (og>>2)*512
              + ((og&3)*16 + (wp&15))*8;
    *(uint4*)((ushort*)K + kidx) = *(uint4*)kv;
  } else {
    int ol = t >> 1, wp0 = (t & 1)*16;
    ushort vv[16];
    #pragma unroll
    for (int j = 0; j < 16; ++j)
      vv[j] = f2bu(fmaxf(Pb[0][ol][wp0 + j], Pb[1][ol][wp0 + j]));
    int n = (o0 - 128) + ol;
    long vbase = (long)(b)*262144 + (px>>1)*16384 + (n>>4)*1024 + (px&1)*512;
    ushort* dst0 = (ushort*)Vt + vbase + ((wp0>>3)*16 + (n&15))*8;
    *(uint4*)dst0         = *(uint4*)(vv);
    *(uint4*)(dst0 + 128) = *(uint4*)(vv + 8);
  }
}

// ---------------- MFMA flash attention v11: 4 independent barrier domains/CU.
// Same per-wave structure as v10 (zero-redundancy PV, fragment-native K/V,
// 1-tile reg prefetch, one barrier per tile) but q-tile 32 rows, 256-thread
// blocks, grid 128x8 = 1024 blocks = 4 blocks/CU. Same 16 waves/CU as v10
// but in 4 independent barrier domains (was 2) -> a block stalled at its
// barrier / on an exposed L2 wait is covered by 3 other blocks' compute.
// Cost: V total L2 traffic doubles (536MB/launch, ~60% of L2 ceiling);
// K issued traffic unchanged (redundancy 4x->2x).
//   QK: wave w -> rt=w&1 (16 rows), kh=w>>1 (32-key half)
//   PV: wave w -> ALL 32 P-rows x 64-col group (cols w*64..w*64+63)
__global__ __launch_bounds__(256) void attn_kernel(
    const bf16* __restrict__ Q, const bf16* __restrict__ K, const bf16* __restrict__ Vt,
    bf16* __restrict__ Y)
{
  __shared__ __align__(16) ushort Ps[2][32*68];
  __shared__ float l_sh[2][32];

  const int t = threadIdx.x;
  const int b = blockIdx.y, q0 = blockIdx.x*32;
  const int lane = t & 63, w = t >> 6;        // 4 waves
  const int ql = lane & 15, quad = lane >> 4;
  const int rt = w & 1;                        // QK row tile (16 rows)
  const int kh = w >> 1;                       // QK key half (32 keys)
  const ushort* Qu = (const ushort*)Q;
  const ushort* Ku = (const ushort*)K;
  const ushort* Vu = (const ushort*)Vt;

  const long qrow = (long)(b*Nn) + q0 + rt*16 + ql;
  short8 aQ0 = *(const short8*)(Qu + qrow*64 + quad*8);
  short8 aQ1 = *(const short8*)(Qu + qrow*64 + 32 + quad*8);

  const ushort* kfp = Ku + ((long)(b*64) + kh*2)*1024 + lane*8;
  // V col group: wave w owns n16 = w*4 .. w*4+3
  const ushort* vfp = Vu + (long)(b)*262144 + (w*4)*1024 + lane*8;

  float lrow[4];
  #pragma unroll
  for (int r = 0; r < 4; ++r) lrow[r] = 0.f;

  f32x4 acc[2][4];                             // [row tile][col 16-group]
  #pragma unroll
  for (int mi = 0; mi < 2; ++mi)
    #pragma unroll
    for (int ci = 0; ci < 4; ++ci) acc[mi][ci] = (f32x4){0.f,0.f,0.f,0.f};

  short8 kf[4], vf[8];
  auto LD_K = [&](int mt){
    #pragma unroll
    for (int ct = 0; ct < 2; ++ct)
      #pragma unroll
      for (int hf = 0; hf < 2; ++hf)
        kf[ct*2+hf] = *(const short8*)(kfp + mt*4096 + ct*1024 + hf*512);
  };
  auto LD_V = [&](int mt){
    #pragma unroll
    for (int ci = 0; ci < 4; ++ci)
      #pragma unroll
      for (int hf = 0; hf < 2; ++hf)
        vf[ci*2+hf] = *(const short8*)(vfp + mt*16384 + ci*1024 + hf*512);
  };
  auto QK = [&](int sel){
    #pragma unroll
    for (int ct = 0; ct < 2; ++ct) {
      int kb = kh*32 + ct*16;
      f32x4 s = (f32x4){0.f,0.f,0.f,0.f};
      s = __builtin_amdgcn_mfma_f32_16x16x32_bf16(aQ0, kf[ct*2],   s, 0, 0, 0);
      s = __builtin_amdgcn_mfma_f32_16x16x32_bf16(aQ1, kf[ct*2+1], s, 0, 0, 0);
      #pragma unroll
      for (int r = 0; r < 4; ++r) {
        float e = __expf(s[r]);
        lrow[r] += e;
        Ps[sel][(rt*16 + quad*4 + r)*68 + kb + ql] = f2bu(e);
      }
    }
  };
  auto PV = [&](int sel){
    #pragma unroll
    for (int mi = 0; mi < 2; ++mi) {
      short8 aP0 = *(const short8*)(&Ps[sel][(mi*16 + ql)*68 + quad*8]);
      short8 aP1 = *(const short8*)(&Ps[sel][(mi*16 + ql)*68 + 32 + quad*8]);
      #pragma unroll
      for (int ci = 0; ci < 4; ++ci) {
        acc[mi][ci] = __builtin_amdgcn_mfma_f32_16x16x32_bf16(aP0, vf[ci*2],   acc[mi][ci], 0, 0, 0);
        acc[mi][ci] = __builtin_amdgcn_mfma_f32_16x16x32_bf16(aP1, vf[ci*2+1], acc[mi][ci], 0, 0, 0);
      }
    }
  };

  LD_K(0);
  LD_V(0);
  QK(0);
  LD_K(1);
  __syncthreads();

  for (int mt = 1; mt < 16; ++mt) {
    PV((mt-1)&1);        // consumes vf (tile mt-1)
    LD_V(mt);            // in flight until next PV
    QK(mt&1);            // consumes kf (tile mt)
    LD_K((mt+1)&15);     // clamped wrap (last reload discarded)
    __syncthreads();
  }
  PV(1);                 // tile 15

  #pragma unroll
  for (int r = 0; r < 4; ++r)
    #pragma unroll
    for (int off = 1; off < 16; off <<= 1)
      lrow[r] += __shfl_xor(lrow[r], off, 64);
  if (ql == 0) {
    #pragma unroll
    for (int r = 0; r < 4; ++r) l_sh[kh][rt*16 + quad*4 + r] = lrow[r];
  }
  __syncthreads();
  ushort* Yu = (ushort*)Y;
  #pragma unroll
  for (int mi = 0; mi < 2; ++mi)
    #pragma unroll
    for (int r = 0; r < 4; ++r) {
      int row = mi*16 + quad*4 + r;
      float inv = 1.f / (l_sh[0][row] + l_sh[1][row]);
      int n = q0 + row;
      #pragma unroll
      for (int ci = 0; ci < 4; ++ci) {
        int c = w*64 + ci*16 + ql;
        long idx = (((long)b*256 + (n>>4))*8 + (c>>5))*512
                 + (((c&31)>>3)*16 + (n&15))*8 + (c&7);
        Yu[idx] = f2bu(acc[mi][ci][r]*inv);
      }
    }
}

// ---------------- wconv: zero-LDS main loop, direct fragments from Wwt/Yt.
__global__ __launch_bounds__(256) void wconv_kernel(
    const bf16* __restrict__ Yt, const bf16* __restrict__ Wwt, const float* __restrict__ Wb,
    const float* __restrict__ gamma, const float* __restrict__ beta,
    const float* __restrict__ mean, const float* __restrict__ var,
    const float* __restrict__ x, float* __restrict__ out)
{
  __shared__ float ssc[128], ssh[128];
  const int t = threadIdx.x;
  const int n0 = blockIdx.x*128, o0 = blockIdx.y*128, b = blockIdx.z;
  const int lane = t & 63, w = t >> 6;
  const int ql = lane & 15, quad = lane >> 4;
  const int wm = (w & 1)*64, wn = (w >> 1)*64;

  if (t < 128) {
    int o = o0 + t;
    float sc = gamma[o] * rsqrtf(var[o] + EPSf);
    ssc[t] = sc;
    ssh[t] = (Wb[o] - mean[o])*sc + beta[o];
  }

  const ushort* aB[4]; const ushort* bB[4];
  #pragma unroll
  for (int mi = 0; mi < 4; ++mi)
    aB[mi] = (const ushort*)Wwt + ((long)(((o0 + wm)>>4) + mi)*8)*512 + lane*8;
  #pragma unroll
  for (int ni = 0; ni < 4; ++ni)
    bB[ni] = (const ushort*)Yt + (((long)b*256 + ((n0 + wn)>>4) + ni)*8)*512 + lane*8;

  f32x4 acc[4][4];
  #pragma unroll
  for (int i = 0; i < 4; ++i)
    #pragma unroll
    for (int j = 0; j < 4; ++j) acc[i][j] = (f32x4){0.f,0.f,0.f,0.f};

  short8 aX[4], bX[4], aY[4], bY[4];
  #pragma unroll
  for (int i = 0; i < 4; ++i) {
    aX[i] = *(const short8*)(aB[i]);
    bX[i] = *(const short8*)(bB[i]);
    aY[i] = *(const short8*)(aB[i] + 512);
    bY[i] = *(const short8*)(bB[i] + 512);
  }
  #pragma unroll
  for (int kc2 = 0; kc2 < 4; ++kc2) {
    #pragma unroll
    for (int mi = 0; mi < 4; ++mi)
      #pragma unroll
      for (int ni = 0; ni < 4; ++ni)
        acc[mi][ni] = __builtin_amdgcn_mfma_f32_16x16x32_bf16(aX[mi], bX[ni], acc[mi][ni], 0, 0, 0);
    if (kc2 < 3) {
      #pragma unroll
      for (int i = 0; i < 4; ++i) {
        aX[i] = *(const short8*)(aB[i] + (kc2*2 + 2)*512);
        bX[i] = *(const short8*)(bB[i] + (kc2*2 + 2)*512);
      }
    }
    #pragma unroll
    for (int mi = 0; mi < 4; ++mi)
      #pragma unroll
      for (int ni = 0; ni < 4; ++ni)
        acc[mi][ni] = __builtin_amdgcn_mfma_f32_16x16x32_bf16(aY[mi], bY[ni], acc[mi][ni], 0, 0, 0);
    if (kc2 < 3) {
      #pragma unroll
      for (int i = 0; i < 4; ++i) {
        aY[i] = *(const short8*)(aB[i] + (kc2*2 + 3)*512);
        bY[i] = *(const short8*)(bB[i] + (kc2*2 + 3)*512);
      }
    }
  }
  __syncthreads();   // ssc/ssh visible to all
  #pragma unroll
  for (int mi = 0; mi < 4; ++mi)
    #pragma unroll
    for (int r = 0; r < 4; ++r) {
      int ol = wm + mi*16 + quad*4 + r;
      int o = o0 + ol;
      float sc = ssc[ol], sh = ssh[ol];
      #pragma unroll
      for (int ni = 0; ni < 4; ++ni) {
        int n = n0 + wn + ni*16 + ql;
        long gidx = ((long)(b*Cn + o))*Nn + n;
        out[gidx] = acc[mi][ni][r]*sc + sh + x[gidx];
      }
    }
}

extern "C" void kernel_launch(void* const* d_in, const int* in_sizes, int n_in,
                              void* d_out, int out_size, void* d_ws, size_t ws_size,
                              hipStream_t stream)
{
  const float* x       = (const float*)d_in[0];
  const float* g_w     = (const float*)d_in[1];
  const float* g_b     = (const float*)d_in[2];
  const float* theta_w = (const float*)d_in[3];
  const float* theta_b = (const float*)d_in[4];
  const float* phi_w   = (const float*)d_in[5];
  const float* phi_b   = (const float*)d_in[6];
  const float* W_w     = (const float*)d_in[7];
  const float* W_b     = (const float*)d_in[8];
  const float* bn_g    = (const float*)d_in[9];
  const float* bn_b    = (const float*)d_in[10];
  const float* bn_m    = (const float*)d_in[11];
  const float* bn_v    = (const float*)d_in[12];
  float* out = (float*)d_out;

  bf16* wsb = (bf16*)d_ws;
  bf16* xTt   = wsb;                  // B*N*C = 8,388,608 (dead after gemm384)
  bf16* Yt    = wsb;                  // alias xTt (tiled layout)
  bf16* Q     = wsb + 8388608;        // B*N*64  = 2,097,152
  bf16* K     = wsb + 10485760;       // B*M*64  =   524,288 (tiled)
  bf16* Vt    = wsb + 11010048;       // B*C*M   = 2,097,152 (tiled)
  bf16* Wct   = wsb + 13107200;       // 384*256 =    98,304 (tiled)
  float* bcomb = (float*)(wsb + 13205504);  // 384 fp32 (= 768 ushorts)
  bf16* Wwt   = wsb + 13206272;       // 256*256 =    65,536 (tiled)

  transpose_kernel<<<dim3(64, 4, Bn), 256, 0, stream>>>(x, xTt);
  wprep_kernel<<<dim3(640), 256, 0, stream>>>(theta_w, theta_b, phi_w, phi_b, g_w, g_b, W_w, Wct, bcomb, Wwt);
  gemm384_kernel<<<dim3(32, 3, Bn), 256, 0, stream>>>(xTt, Wct, bcomb, Q, K, Vt);
  attn_kernel<<<dim3(128, Bn), 256, 0, stream>>>(Q, K, Vt, Yt);
  wconv_kernel<<<dim3(32, 2, Bn), 256, 0, stream>>>(Yt, Wwt, W_b, bn_g, bn_b, bn_m, bn_v, x, out);
}

// Round 13
// 164.870 us; speedup vs baseline: 1.0692x; 1.0692x over previous
//
#include <hip/hip_runtime.h>
#include <hip/hip_bf16.h>

typedef __hip_bfloat16 bf16;
typedef unsigned short ushort;
typedef unsigned int uint;
typedef __attribute__((ext_vector_type(8))) short short8;
typedef __attribute__((ext_vector_type(4))) float f32x4;

#define Bn 8
#define Cn 256
#define Nn 4096          // H*W
#define Mn 1024          // pooled
#define EPSf 1e-5f

__device__ __forceinline__ float b2f(const bf16 v){ return __bfloat162float(v); }
__device__ __forceinline__ ushort f2bu(float f){
  uint u = __float_as_uint(f);
  return (ushort)((u + 0x7FFFu + ((u >> 16) & 1u)) >> 16);
}

// ---- fragment-tiled layouts (1KB contiguous lane-linear blocks, v8-proven) ----
// xTt: (b, p16, kc)  idx = ((b*256+p16)*8+kc)*512 + lane*8
// Wct/Wwt: (o16, kc) idx = (o16*8+kc)*512 + lane*8
// K:  (b, k16, half) idx = ((b*64+k16)*2+half)*512 + lane*8
// Vt: (b, mt, n16, half) idx = (((b*16+mt)*16+n16)*2+half)*512 + lane*8

// ---------------- transpose: x[b][c][p] fp32 -> xTt fragment-tiled bf16
__global__ __launch_bounds__(256) void transpose_kernel(
    const float* __restrict__ x, bf16* __restrict__ xT)
{
  __shared__ float xs[64][65];
  const int t = threadIdx.x;
  const int p0 = blockIdx.x*64, c0 = blockIdx.y*64, b = blockIdx.z;
  #pragma unroll
  for (int i = 0; i < 16; ++i) {
    int idx = t + i*256; int cl = idx >> 6, pl = idx & 63;
    xs[cl][pl] = x[((long)(b*Cn) + c0 + cl)*Nn + p0 + pl];
  }
  __syncthreads();
  ushort* xt = (ushort*)xT;
  const int ql = t & 15, quad = (t >> 4) & 3, w = t >> 6;
  #pragma unroll
  for (int i = 0; i < 2; ++i) {
    int f = w + i*4;                  // 0..7
    int p16f = f >> 1, kcf = f & 1;
    int pl = p16f*16 + ql;
    int ch0 = kcf*32 + quad*8;
    uint u[4];
    #pragma unroll
    for (int k = 0; k < 4; ++k)
      u[k] = (uint)f2bu(xs[ch0 + 2*k][pl]) | ((uint)f2bu(xs[ch0 + 2*k + 1][pl]) << 16);
    long base = ((long)b*2048 + ((p0>>4) + p16f)*8 + (c0>>5) + kcf)*512;
    *(uint4*)(xt + base + (t & 63)*8) = make_uint4(u[0], u[1], u[2], u[3]);
  }
}

// ---------------- merged prep: combined weights -> tiled Wct + bcomb,
// and W_w -> tiled Wwt.  grid 640: r<384 = Wct row r; r>=384 = Wwt row r-384.
__global__ __launch_bounds__(256) void wprep_kernel(
    const float* __restrict__ tw, const float* __restrict__ tb,
    const float* __restrict__ pw, const float* __restrict__ pb,
    const float* __restrict__ gw, const float* __restrict__ gb,
    const float* __restrict__ Ww,
    bf16* __restrict__ Wcomb, float* __restrict__ bcomb,
    bf16* __restrict__ Wwt)
{
  const int rb = blockIdx.x, c = threadIdx.x;
  if (rb < 384) {
    const int r = rb;
    float v;
    if (r < 64)        v = (c < 64)  ? tw[r*64 + c]            : 0.f;
    else if (r < 128)  v = (c >= 64) ? pw[(r-64)*192 + (c-64)] : 0.f;
    else               v = gw[(r-128)*256 + c];
    ((ushort*)Wcomb)[((r>>4)*8 + (c>>5))*512 + (((c&31)>>3)*16 + (r&15))*8 + (c&7)]
        = f2bu(v);
    if (c == 0)
      bcomb[r] = (r < 64) ? tb[r] : (r < 128) ? pb[r-64] : gb[r-128];
  } else {
    const int r = rb - 384;
    ((ushort*)Wwt)[((r>>4)*8 + (c>>5))*512 + (((c&31)>>3)*16 + (r&15))*8 + (c&7)]
        = f2bu(Ww[r*256 + c]);
  }
}

// ---------------- fused front GEMM + pooling: zero-LDS main loop (round-6).
__global__ __launch_bounds__(256) void gemm384_kernel(
    const bf16* __restrict__ xTt, const bf16* __restrict__ Wct,
    const float* __restrict__ bcomb, bf16* __restrict__ Q,
    bf16* __restrict__ K, bf16* __restrict__ Vt)
{
  __shared__ float Pb[2][128][33];
  const int t = threadIdx.x;
  const int px = blockIdx.x, o0 = blockIdx.y*128, b = blockIdx.z;
  const int p0 = px*128;
  const int lane = t & 63, w = t >> 6;
  const int ql = lane & 15, quad = lane >> 4;
  const int wm = (w & 1)*64, wn = (w >> 1)*64;
  const ushort* xu = (const ushort*)xTt;
  const ushort* wu = (const ushort*)Wct;

  const ushort* aB[4]; const ushort* bB[4];
  #pragma unroll
  for (int mi = 0; mi < 4; ++mi)
    aB[mi] = xu + (((long)b*256 + px*8 + (wm>>4) + mi)*8)*512 + lane*8;
  #pragma unroll
  for (int ni = 0; ni < 4; ++ni)
    bB[ni] = wu + ((long)(((o0 + wn)>>4) + ni)*8)*512 + lane*8;

  f32x4 acc[4][4];
  #pragma unroll
  for (int i = 0; i < 4; ++i)
    #pragma unroll
    for (int j = 0; j < 4; ++j) acc[i][j] = (f32x4){0.f,0.f,0.f,0.f};

  short8 aX[4], bX[4], aY[4], bY[4];
  #pragma unroll
  for (int i = 0; i < 4; ++i) {
    aX[i] = *(const short8*)(aB[i]);
    bX[i] = *(const short8*)(bB[i]);
    aY[i] = *(const short8*)(aB[i] + 512);
    bY[i] = *(const short8*)(bB[i] + 512);
  }
  #pragma unroll
  for (int kc2 = 0; kc2 < 4; ++kc2) {
    #pragma unroll
    for (int mi = 0; mi < 4; ++mi)
      #pragma unroll
      for (int ni = 0; ni < 4; ++ni)
        acc[mi][ni] = __builtin_amdgcn_mfma_f32_16x16x32_bf16(aX[mi], bX[ni], acc[mi][ni], 0, 0, 0);
    if (kc2 < 3) {
      #pragma unroll
      for (int i = 0; i < 4; ++i) {
        aX[i] = *(const short8*)(aB[i] + (kc2*2 + 2)*512);
        bX[i] = *(const short8*)(bB[i] + (kc2*2 + 2)*512);
      }
    }
    #pragma unroll
    for (int mi = 0; mi < 4; ++mi)
      #pragma unroll
      for (int ni = 0; ni < 4; ++ni)
        acc[mi][ni] = __builtin_amdgcn_mfma_f32_16x16x32_bf16(aY[mi], bY[ni], acc[mi][ni], 0, 0, 0);
    if (kc2 < 3) {
      #pragma unroll
      for (int i = 0; i < 4; ++i) {
        aY[i] = *(const short8*)(aB[i] + (kc2*2 + 3)*512);
        bY[i] = *(const short8*)(bB[i] + (kc2*2 + 3)*512);
      }
    }
  }

  float bias[4];
  #pragma unroll
  for (int ni = 0; ni < 4; ++ni) bias[ni] = bcomb[o0 + wn + ni*16 + ql];

  if (o0 == 0 && wn == 0) {
    #pragma unroll
    for (int mi = 0; mi < 4; ++mi)
      #pragma unroll
      for (int ni = 0; ni < 4; ++ni)
        #pragma unroll
        for (int r = 0; r < 4; ++r) {
          int p = p0 + wm + mi*16 + quad*4 + r;
          Q[((long)(b*Nn) + p)*64 + ni*16 + ql] = __float2bfloat16(acc[mi][ni][r] + bias[ni]);
        }
  }
  __syncthreads();
  if (o0 != 0 || wn == 64) {
    int g = w & 1;
    #pragma unroll
    for (int mi = 0; mi < 4; ++mi)
      #pragma unroll
      for (int ni = 0; ni < 4; ++ni) {
        float a0 = acc[mi][ni][0] + bias[ni], a1 = acc[mi][ni][1] + bias[ni];
        float a2 = acc[mi][ni][2] + bias[ni], a3 = acc[mi][ni][3] + bias[ni];
        int o = wn + ni*16 + ql;
        int wp = mi*8 + quad*2;
        Pb[g][o][wp]     = fmaxf(a0, a1);
        Pb[g][o][wp + 1] = fmaxf(a2, a3);
      }
  }
  __syncthreads();
  if (o0 == 0) {
    int wp = t & 31, og = t >> 5;
    ushort kv[8];
    #pragma unroll
    for (int j = 0; j < 8; ++j) {
      int o = 64 + og*8 + j;
      kv[j] = f2bu(fmaxf(Pb[0][o][wp], Pb[1][o][wp]));
    }
    long kidx = ((long)(b*64) + px*2 + (wp>>4))*1024 + (og>>2)*512
              + ((og&3)*16 + (wp&15))*8;
    *(uint4*)((ushort*)K + kidx) = *(uint4*)kv;
  } else {
    int ol = t >> 1, wp0 = (t & 1)*16;
    ushort vv[16];
    #pragma unroll
    for (int j = 0; j < 16; ++j)
      vv[j] = f2bu(fmaxf(Pb[0][ol][wp0 + j], Pb[1][ol][wp0 + j]));
    int n = (o0 - 128) + ol;
    long vbase = (long)(b)*262144 + (px>>1)*16384 + (n>>4)*1024 + (px&1)*512;
    ushort* dst0 = (ushort*)Vt + vbase + ((wp0>>3)*16 + (n&15))*8;
    *(uint4*)dst0         = *(uint4*)(vv);
    *(uint4*)(dst0 + 128) = *(uint4*)(vv + 8);
  }
}

// ---------------- MFMA flash attention v10 (restored; session-best config):
// 64-row q-tile, 512-thread blocks, 2 blocks/CU. Zero-redundancy PV
// (wave w -> ALL 64 P-rows x 32-col group), fragment-native K/V direct from
// L2, Ps double-buffered, one barrier per tile, 1-tile reg prefetch.
// Block-size axis fully explored: 1 blk/CU (v9) spills + no overlap;
// 4 blk/CU (v11) VALU-bound (per-wave overhead amortized over half the
// MFMA work). 2 blk/CU is the optimum.
//   QK: wave w -> rt=w&3 (16 rows), kh=w>>2 (32-key half)
//   PV: wave w -> ALL 64 P-rows x 32-col group (cols w*32..w*32+31)
__global__ __launch_bounds__(512) void attn_kernel(
    const bf16* __restrict__ Q, const bf16* __restrict__ K, const bf16* __restrict__ Vt,
    bf16* __restrict__ Y)
{
  __shared__ __align__(16) ushort Ps[2][64*68];
  __shared__ float l_sh[2][64];

  const int t = threadIdx.x;
  const int b = blockIdx.y, q0 = blockIdx.x*64;
  const int lane = t & 63, w = t >> 6;        // 8 waves
  const int ql = lane & 15, quad = lane >> 4;
  const int rt = w & 3;                        // QK row tile (16 rows)
  const int kh = w >> 2;                       // QK key half (32 keys)
  const ushort* Qu = (const ushort*)Q;
  const ushort* Ku = (const ushort*)K;
  const ushort* Vu = (const ushort*)Vt;

  const long qrow = (long)(b*Nn) + q0 + rt*16 + ql;
  short8 aQ0 = *(const short8*)(Qu + qrow*64 + quad*8);
  short8 aQ1 = *(const short8*)(Qu + qrow*64 + 32 + quad*8);

  const ushort* kfp = Ku + ((long)(b*64) + kh*2)*1024 + lane*8;
  // V col group: wave w owns n16 = w*2, w*2+1
  const ushort* vfp = Vu + (long)(b)*262144 + (w*2)*1024 + lane*8;

  float lrow[4];
  #pragma unroll
  for (int r = 0; r < 4; ++r) lrow[r] = 0.f;

  f32x4 acc[4][2];                             // [row tile][col 16-group]
  #pragma unroll
  for (int mi = 0; mi < 4; ++mi)
    #pragma unroll
    for (int ci = 0; ci < 2; ++ci) acc[mi][ci] = (f32x4){0.f,0.f,0.f,0.f};

  short8 kf[4], vf[4];
  auto LD_K = [&](int mt){
    #pragma unroll
    for (int ct = 0; ct < 2; ++ct)
      #pragma unroll
      for (int hf = 0; hf < 2; ++hf)
        kf[ct*2+hf] = *(const short8*)(kfp + mt*4096 + ct*1024 + hf*512);
  };
  auto LD_V = [&](int mt){
    #pragma unroll
    for (int ci = 0; ci < 2; ++ci)
      #pragma unroll
      for (int hf = 0; hf < 2; ++hf)
        vf[ci*2+hf] = *(const short8*)(vfp + mt*16384 + ci*1024 + hf*512);
  };
  auto QK = [&](int sel){
    #pragma unroll
    for (int ct = 0; ct < 2; ++ct) {
      int kb = kh*32 + ct*16;
      f32x4 s = (f32x4){0.f,0.f,0.f,0.f};
      s = __builtin_amdgcn_mfma_f32_16x16x32_bf16(aQ0, kf[ct*2],   s, 0, 0, 0);
      s = __builtin_amdgcn_mfma_f32_16x16x32_bf16(aQ1, kf[ct*2+1], s, 0, 0, 0);
      #pragma unroll
      for (int r = 0; r < 4; ++r) {
        float e = __expf(s[r]);
        lrow[r] += e;
        Ps[sel][(rt*16 + quad*4 + r)*68 + kb + ql] = f2bu(e);
      }
    }
  };
  auto PV = [&](int sel){
    #pragma unroll
    for (int mi = 0; mi < 4; ++mi) {
      short8 aP0 = *(const short8*)(&Ps[sel][(mi*16 + ql)*68 + quad*8]);
      short8 aP1 = *(const short8*)(&Ps[sel][(mi*16 + ql)*68 + 32 + quad*8]);
      #pragma unroll
      for (int ci = 0; ci < 2; ++ci) {
        acc[mi][ci] = __builtin_amdgcn_mfma_f32_16x16x32_bf16(aP0, vf[ci*2],   acc[mi][ci], 0, 0, 0);
        acc[mi][ci] = __builtin_amdgcn_mfma_f32_16x16x32_bf16(aP1, vf[ci*2+1], acc[mi][ci], 0, 0, 0);
      }
    }
  };

  LD_K(0);
  LD_V(0);
  QK(0);
  LD_K(1);
  __syncthreads();

  for (int mt = 1; mt < 16; ++mt) {
    PV((mt-1)&1);        // consumes vf (tile mt-1)
    LD_V(mt);            // in flight until next PV
    QK(mt&1);            // consumes kf (tile mt)
    LD_K((mt+1)&15);     // clamped wrap (last reload discarded)
    __syncthreads();
  }
  PV(1);                 // tile 15

  #pragma unroll
  for (int r = 0; r < 4; ++r)
    #pragma unroll
    for (int off = 1; off < 16; off <<= 1)
      lrow[r] += __shfl_xor(lrow[r], off, 64);
  if (ql == 0) {
    #pragma unroll
    for (int r = 0; r < 4; ++r) l_sh[kh][rt*16 + quad*4 + r] = lrow[r];
  }
  __syncthreads();
  ushort* Yu = (ushort*)Y;
  #pragma unroll
  for (int mi = 0; mi < 4; ++mi)
    #pragma unroll
    for (int r = 0; r < 4; ++r) {
      int row = mi*16 + quad*4 + r;
      float inv = 1.f / (l_sh[0][row] + l_sh[1][row]);
      int n = q0 + row;
      #pragma unroll
      for (int ci = 0; ci < 2; ++ci) {
        int c = w*32 + ci*16 + ql;
        long idx = (((long)b*256 + (n>>4))*8 + (c>>5))*512
                 + (((c&31)>>3)*16 + (n&15))*8 + (c&7);
        Yu[idx] = f2bu(acc[mi][ci][r]*inv);
      }
    }
}

// ---------------- wconv: zero-LDS main loop, direct fragments from Wwt/Yt.
__global__ __launch_bounds__(256) void wconv_kernel(
    const bf16* __restrict__ Yt, const bf16* __restrict__ Wwt, const float* __restrict__ Wb,
    const float* __restrict__ gamma, const float* __restrict__ beta,
    const float* __restrict__ mean, const float* __restrict__ var,
    const float* __restrict__ x, float* __restrict__ out)
{
  __shared__ float ssc[128], ssh[128];
  const int t = threadIdx.x;
  const int n0 = blockIdx.x*128, o0 = blockIdx.y*128, b = blockIdx.z;
  const int lane = t & 63, w = t >> 6;
  const int ql = lane & 15, quad = lane >> 4;
  const int wm = (w & 1)*64, wn = (w >> 1)*64;

  if (t < 128) {
    int o = o0 + t;
    float sc = gamma[o] * rsqrtf(var[o] + EPSf);
    ssc[t] = sc;
    ssh[t] = (Wb[o] - mean[o])*sc + beta[o];
  }

  const ushort* aB[4]; const ushort* bB[4];
  #pragma unroll
  for (int mi = 0; mi < 4; ++mi)
    aB[mi] = (const ushort*)Wwt + ((long)(((o0 + wm)>>4) + mi)*8)*512 + lane*8;
  #pragma unroll
  for (int ni = 0; ni < 4; ++ni)
    bB[ni] = (const ushort*)Yt + (((long)b*256 + ((n0 + wn)>>4) + ni)*8)*512 + lane*8;

  f32x4 acc[4][4];
  #pragma unroll
  for (int i = 0; i < 4; ++i)
    #pragma unroll
    for (int j = 0; j < 4; ++j) acc[i][j] = (f32x4){0.f,0.f,0.f,0.f};

  short8 aX[4], bX[4], aY[4], bY[4];
  #pragma unroll
  for (int i = 0; i < 4; ++i) {
    aX[i] = *(const short8*)(aB[i]);
    bX[i] = *(const short8*)(bB[i]);
    aY[i] = *(const short8*)(aB[i] + 512);
    bY[i] = *(const short8*)(bB[i] + 512);
  }
  #pragma unroll
  for (int kc2 = 0; kc2 < 4; ++kc2) {
    #pragma unroll
    for (int mi = 0; mi < 4; ++mi)
      #pragma unroll
      for (int ni = 0; ni < 4; ++ni)
        acc[mi][ni] = __builtin_amdgcn_mfma_f32_16x16x32_bf16(aX[mi], bX[ni], acc[mi][ni], 0, 0, 0);
    if (kc2 < 3) {
      #pragma unroll
      for (int i = 0; i < 4; ++i) {
        aX[i] = *(const short8*)(aB[i] + (kc2*2 + 2)*512);
        bX[i] = *(const short8*)(bB[i] + (kc2*2 + 2)*512);
      }
    }
    #pragma unroll
    for (int mi = 0; mi < 4; ++mi)
      #pragma unroll
      for (int ni = 0; ni < 4; ++ni)
        acc[mi][ni] = __builtin_amdgcn_mfma_f32_16x16x32_bf16(aY[mi], bY[ni], acc[mi][ni], 0, 0, 0);
    if (kc2 < 3) {
      #pragma unroll
      for (int i = 0; i < 4; ++i) {
        aY[i] = *(const short8*)(aB[i] + (kc2*2 + 3)*512);
        bY[i] = *(const short8*)(bB[i] + (kc2*2 + 3)*512);
      }
    }
  }
  __syncthreads();   // ssc/ssh visible to all
  #pragma unroll
  for (int mi = 0; mi < 4; ++mi)
    #pragma unroll
    for (int r = 0; r < 4; ++r) {
      int ol = wm + mi*16 + quad*4 + r;
      int o = o0 + ol;
      float sc = ssc[ol], sh = ssh[ol];
      #pragma unroll
      for (int ni = 0; ni < 4; ++ni) {
        int n = n0 + wn + ni*16 + ql;
        long gidx = ((long)(b*Cn + o))*Nn + n;
        out[gidx] = acc[mi][ni][r]*sc + sh + x[gidx];
      }
    }
}

extern "C" void kernel_launch(void* const* d_in, const int* in_sizes, int n_in,
                              void* d_out, int out_size, void* d_ws, size_t ws_size,
                              hipStream_t stream)
{
  const float* x       = (const float*)d_in[0];
  const float* g_w     = (const float*)d_in[1];
  const float* g_b     = (const float*)d_in[2];
  const float* theta_w = (const float*)d_in[3];
  const float* theta_b = (const float*)d_in[4];
  const float* phi_w   = (const float*)d_in[5];
  const float* phi_b   = (const float*)d_in[6];
  const float* W_w     = (const float*)d_in[7];
  const float* W_b     = (const float*)d_in[8];
  const float* bn_g    = (const float*)d_in[9];
  const float* bn_b    = (const float*)d_in[10];
  const float* bn_m    = (const float*)d_in[11];
  const float* bn_v    = (const float*)d_in[12];
  float* out = (float*)d_out;

  bf16* wsb = (bf16*)d_ws;
  bf16* xTt   = wsb;                  // B*N*C = 8,388,608 (dead after gemm384)
  bf16* Yt    = wsb;                  // alias xTt (tiled layout)
  bf16* Q     = wsb + 8388608;        // B*N*64  = 2,097,152
  bf16* K     = wsb + 10485760;       // B*M*64  =   524,288 (tiled)
  bf16* Vt    = wsb + 11010048;       // B*C*M   = 2,097,152 (tiled)
  bf16* Wct   = wsb + 13107200;       // 384*256 =    98,304 (tiled)
  float* bcomb = (float*)(wsb + 13205504);  // 384 fp32 (= 768 ushorts)
  bf16* Wwt   = wsb + 13206272;       // 256*256 =    65,536 (tiled)

  transpose_kernel<<<dim3(64, 4, Bn), 256, 0, stream>>>(x, xTt);
  wprep_kernel<<<dim3(640), 256, 0, stream>>>(theta_w, theta_b, phi_w, phi_b, g_w, g_b, W_w, Wct, bcomb, Wwt);
  gemm384_kernel<<<dim3(32, 3, Bn), 256, 0, stream>>>(xTt, Wct, bcomb, Q, K, Vt);
  attn_kernel<<<dim3(64, Bn), 512, 0, stream>>>(Q, K, Vt, Yt);
  wconv_kernel<<<dim3(32, 2, Bn), 256, 0, stream>>>(Yt, Wwt, W_b, bn_g, bn_b, bn_m, bn_v, x, out);
}